// Round 4
// baseline (2014.152 us; speedup 1.0000x reference)
//
#include <hip/hip_runtime.h>
#include <hip/hip_fp16.h>

#define DT 5e-5f
#define SPRING_Y 30000.0f
#define DASHPOT 100.0f
// exp(-DT * DRAG_DAMPING) = exp(-5e-5)
#define DRAG 0.9999500012499792f
#define NSUB 100

// xv layout: xv[2*i] = position, xv[2*i+1] = velocity (w unused); 32B/vertex.
// adj entry: 4B: (neighbor_idx:17) << 15 | (fp16(1/rest) & 0x7fff).
// Row: vertex v's entries at adj[v*64 .. v*64+deg[v]); row = 16 uint4 quads.
// R14 (= R13 minus the cooperative kernel, which hung the container):
// 4 lanes/vertex (2 pairs). Superiter u: pair k owns quad 2u+k (one uint4,
// both pair lanes load the same 16B); 8 entries/vertex/superiter -> padded
// eval waste ~20% (R2's 16-entry grain was ~60%). pad_k fills each row to its
// 8-boundary with duplicates of entry 0, so padded evals gather a line this
// vertex's lanes already touched (L1 hit, no garbage random fetches).
// 100 per-substep launches; no co-residency assumptions anywhere.

// ---------- build ----------

__global__ void init_k(const float* __restrict__ x0, float4* __restrict__ xv,
                       int* __restrict__ deg, int nv) {
    int i = blockIdx.x * blockDim.x + threadIdx.x;
    if (i < nv) {
        xv[2 * i]     = make_float4(x0[3 * i], x0[3 * i + 1], x0[3 * i + 2], 0.0f);
        xv[2 * i + 1] = make_float4(0.0f, 0.0f, 0.0f, 0.0f);
        deg[i] = 0;
    }
}

__global__ void fill_sliced_k(const int2* __restrict__ springs,
                              const float* __restrict__ rest,
                              int* __restrict__ deg, unsigned* __restrict__ adj,
                              int ns, int nv, int S) {
    int b = blockIdx.x;
    int slice = b & 7;
    int s = (b >> 3) * blockDim.x + threadIdx.x;
    if (s >= ns) return;

    int lo = (int)(((long long)slice * nv) >> 3);
    int hi = (int)(((long long)(slice + 1) * nv) >> 3);

    int2 p = springs[s];
    unsigned h = __half_as_ushort(__float2half(1.0f / rest[s])) & 0x7fffu;
    if (p.x >= lo && p.x < hi) {
        int a = atomicAdd(&deg[p.x], 1);
        adj[p.x * S + a] = ((unsigned)p.y << 15) | h;
    }
    if (p.y >= lo && p.y < hi) {
        int c = atomicAdd(&deg[p.y], 1);
        adj[p.y * S + c] = ((unsigned)p.x << 15) | h;
    }
}

// pad each row to its 8-entry boundary with duplicates of entry 0 (valid
// index; the dup's xv line is one this vertex's lanes already fetch -> L1
// hit; msk=0 kills its force contribution).
__global__ void pad_k(const int* __restrict__ deg, unsigned* __restrict__ adj,
                      int nv) {
    int v = blockIdx.x * blockDim.x + threadIdx.x;
    if (v >= nv) return;
    int d = deg[v];
    int e = (d + 7) & ~7;
    if (d == 0 || d == e) return;
    unsigned dup = adj[v * 64];
    for (int j = d; j < e; ++j) adj[v * 64 + j] = dup;
}

// ---------- fused per-substep kernel ----------

// one eval: lane computes its OWN entry's spring contribution.
// t1 = xin[2*nA + par]   (even lane: pos(A); odd lane: vel(A))
// t2 = xin[2*nB + 1-par] (even lane: vel(B); odd lane: pos(B))
__device__ __forceinline__ void spring_accum(
        int par, unsigned e, float msk, float4 t1, float4 t2,
        const float4& xa, const float4& va,
        float& fx, float& fy, float& fz) {
    float invr = __uint_as_float(((e & 0x7fffu) << 13) + (112u << 23));
    float xbx = par ? t2.x : t1.x;     // own neighbor's position
    float xby = par ? t2.y : t1.y;
    float xbz = par ? t2.z : t1.z;
    float ux  = par ? t1.x : t2.x;     // half this lane must SEND (partner's vel)
    float uy  = par ? t1.y : t2.y;
    float uz  = par ? t1.z : t2.z;
    float vbx = __shfl_xor(ux, 1);     // own neighbor's velocity
    float vby = __shfl_xor(uy, 1);
    float vbz = __shfl_xor(uz, 1);

    float dx = xbx - xa.x, dy = xby - xa.y, dz = xbz - xa.z;
    float len = sqrtf(dx * dx + dy * dy + dz * dz);
    float il = 1.0f / len;             // post-pad all entries valid: len > 0
    float ddx = dx * il, ddy = dy * il, ddz = dz * il;
    float vrel = (vbx - va.x) * ddx + (vby - va.y) * ddy + (vbz - va.z) * ddz;
    float coef = (SPRING_Y * (len * invr - 1.0f) + DASHPOT * vrel) * msk;
    fx += coef * ddx;
    fy += coef * ddy;
    fz += coef * ddz;
}

__global__ void __launch_bounds__(256) substep4_k(
        const float4* __restrict__ xvin, float4* __restrict__ xvout,
        const uint4* __restrict__ adjq, const int* __restrict__ deg,
        const float* __restrict__ mass, int nv, float* __restrict__ out) {
    int gid = blockIdx.x * blockDim.x + threadIdx.x;
    int vid = gid >> 2;
    int sub = gid & 3;
    if (vid >= nv) return;
    int par = sub & 1;                 // lane parity within its pair
    int k   = sub >> 1;                // pair index 0..1

    float4 xa = xvin[2 * vid];
    float4 va = xvin[2 * vid + 1];
    float m = mass[vid];               // hoisted: overlaps with loop latency
    int d = deg[vid];
    int niter = (d + 7) >> 3;          // superiterations (uniform per vertex)
    const uint4* rowq = adjq + (size_t)vid * 16;

    float fx = 0.0f, fy = 0.0f, fz = 0.0f;

    for (int u = 0; u < niter; ++u) {
        uint4 q = rowq[2 * u + k];     // pair's quad: one 16B load
        int nA0 = (int)(q.x >> 15), nB0 = (int)(q.y >> 15);
        int nA1 = (int)(q.z >> 15), nB1 = (int)(q.w >> 15);

        // cooperative line fetches (1 line-touch per eval)
        float4 t10 = xvin[2 * nA0 + par];
        float4 t20 = xvin[2 * nB0 + (1 - par)];
        float4 t11 = xvin[2 * nA1 + par];
        float4 t21 = xvin[2 * nB1 + (1 - par)];

        int base = 8 * u + 4 * k;
        float msk0 = (base + par < d) ? 1.0f : 0.0f;
        spring_accum(par, par ? q.y : q.x, msk0, t10, t20, xa, va, fx, fy, fz);
        float msk1 = (base + 2 + par < d) ? 1.0f : 0.0f;
        spring_accum(par, par ? q.w : q.z, msk1, t11, t21, xa, va, fx, fy, fz);
    }

    // reduce across the 4 lanes of this vertex (xor stays within the group)
    fx += __shfl_xor(fx, 1); fx += __shfl_xor(fx, 2);
    fy += __shfl_xor(fy, 1); fy += __shfl_xor(fy, 2);
    fz += __shfl_xor(fz, 1); fz += __shfl_xor(fz, 2);

    if (sub == 0) {
        fz += m * (-9.8f);
        float invm = 1.0f / m;

        va.x = (va.x + DT * fx * invm) * DRAG;
        va.y = (va.y + DT * fy * invm) * DRAG;
        va.z = (va.z + DT * fz * invm) * DRAG;

        xa.x += DT * va.x;
        xa.y += DT * va.y;
        xa.z += DT * va.z;
        xa.z = fmaxf(xa.z, 0.0f);
        if (xa.z == 0.0f) va.z = 0.0f;

        xvout[2 * vid]     = xa;
        xvout[2 * vid + 1] = va;

        if (out) {                     // final substep: emit packed (NV,3) output
            out[3 * vid + 0] = xa.x;
            out[3 * vid + 1] = xa.y;
            out[3 * vid + 2] = xa.z;
        }
    }
}

extern "C" void kernel_launch(void* const* d_in, const int* in_sizes, int n_in,
                              void* d_out, int out_size, void* d_ws, size_t ws_size,
                              hipStream_t stream) {
    const float* x0      = (const float*)d_in[0];   // (NV,3) fp32
    const int2*  springs = (const int2*)d_in[1];    // (NS,2) int32
    const float* rest    = (const float*)d_in[2];   // (NS,)  fp32
    const float* mass    = (const float*)d_in[3];   // (NV,)  fp32

    const int ns = in_sizes[2];        // 1,000,000
    const int nv = in_sizes[3];        // 100,000
    const int nb = (nv + 255) / 256;

    // workspace layout
    char* ws = (char*)d_ws;
    size_t o = 0;
    float4* xva   = (float4*)(ws + o); o += (size_t)nv * 32;   // x,v interleaved
    float4* xvb   = (float4*)(ws + o); o += (size_t)nv * 32;
    int* deg      = (int*)(ws + o);    o += (((size_t)nv * 4 + 15) & ~15ull);
    unsigned* adj = (unsigned*)(ws + o);                       // nv*64*4B, 16B-aligned

    const int STRIDE = 64;

    dim3 blk(256);
    init_k<<<dim3(nb), blk, 0, stream>>>(x0, xva, deg, nv);
    fill_sliced_k<<<dim3(8 * ((ns + 255) / 256)), blk, 0, stream>>>(
        springs, rest, deg, adj, ns, nv, STRIDE);
    pad_k<<<dim3(nb), blk, 0, stream>>>(deg, adj, nv);

    const int pblocks = (nv * 4 + 255) / 256;      // 4 lanes per vertex
    float4* xi = xva;
    float4* xo = xvb;
    for (int t = 0; t < NSUB; ++t) {
        float* out = (t == NSUB - 1) ? (float*)d_out : nullptr;
        substep4_k<<<dim3(pblocks), blk, 0, stream>>>(
            xi, xo, (const uint4*)adj, deg, mass, nv, out);
        float4* tmp = xi; xi = xo; xo = tmp;
    }
}